// Round 3
// baseline (259.798 us; speedup 1.0000x reference)
//
#include <hip/hip_runtime.h>
#include <math.h>

#define TPB 256
#define EPT 16      // elements per thread
#define NN  4096    // row length (fixed by problem)
#define KSEL 410    // K = round(4096 * 0.1)

// Monotonic float->uint key: larger float => larger unsigned key.
__device__ __forceinline__ unsigned sortkey(float f) {
    unsigned u = __float_as_uint(f);
    unsigned m = (unsigned)(((int)u) >> 31);     // 0x00000000 or 0xFFFFFFFF
    return u ^ (m | 0x80000000u);
}

template <bool USE_WS>
__global__ __launch_bounds__(TPB)
void skw_main(const float* __restrict__ x, const float* __restrict__ g,
              float* __restrict__ out, float* __restrict__ rowH,
              float* __restrict__ entAcc, float invB)
{
    const int row  = blockIdx.x;
    const int t    = threadIdx.x;
    const int w    = t >> 6;          // wave id 0..3
    const int lane = t & 63;
    const size_t base = (size_t)row * NN + (size_t)t * EPT;

    unsigned key[EPT];
    unsigned bp[EPT / 4];             // 16 value-domain bins, byte-packed

    __shared__ unsigned hist0[256][8];   // bin pass: 8-slot sub-binned (slot = lane&7)
    __shared__ unsigned histr[4][256];   // candidate radix: per-wave
    __shared__ unsigned wtot[4];
    __shared__ float    fred[8];
    __shared__ unsigned sh_digit, sh_above;

    const float4* xp = reinterpret_cast<const float4*>(x + base);
    const float4* gp = reinterpret_cast<const float4*>(g + base);

    // ---- load; entropy partials; exact s = x/10 + g (Markstein div-by-10); value bins ----
    float sZ = 0.f, sZL = 0.f;
#pragma unroll
    for (int q = 0; q < EPT / 4; ++q) {
        float4 xx = xp[q];
        float4 gg = gp[q];
        float xa[4] = {xx.x, xx.y, xx.z, xx.w};
        float ga[4] = {gg.x, gg.y, gg.z, gg.w};
        unsigned pk = 0;
#pragma unroll
        for (int jj = 0; jj < 4; ++jj) {
            float xs = xa[jj];
            float l  = xs * 0.1f;                 // y0 = RN(x * RN(0.1))
            float e  = __expf(l);
            sZ  += e;
            sZL += e * l;
            // correctly-rounded x/10: q = y0 + (x - 10*y0)*r  (exact; x/10 never at f32 midpoint)
            float q10 = __builtin_fmaf(__builtin_fmaf(-10.0f, l, xs), 0.1f, l);
            float s = q10 + ga[jj];
            key[4 * q + jj] = sortkey(s);
            int b = (int)__builtin_fmaf(s, 16.0f, 64.0f);   // (s+4)*16
            b = min(max(b, 0), 255);
            pk |= (unsigned)b << (8 * jj);
        }
        bp[q] = pk;
    }

    // ---- entropy reduce (m = 0 is safe: |x*0.1| < ~0.6) ----
#pragma unroll
    for (int sft = 32; sft >= 1; sft >>= 1) { sZ += __shfl_xor(sZ, sft); sZL += __shfl_xor(sZL, sft); }
    if (lane == 0) { fred[w] = sZ; fred[4 + w] = sZL; }

    // zero bin histogram (2048 words)
    unsigned* h0 = &hist0[0][0];
#pragma unroll
    for (int i = 0; i < 8; ++i) h0[t + 256 * i] = 0;
    __syncthreads();                                   // B1

    if (t == 0) {
        float Z = fred[0] + fred[1] + fred[2] + fred[3];
        float L = fred[4] + fred[5] + fred[6] + fred[7];
        float H = __logf(Z) - L / Z;                   // H = lnZ - E[l]
        if (USE_WS) rowH[row] = H;
        else atomicAdd(entAcc, H * invB);
    }

    // ---- value-bin histogram (near-uniform bins; 8-way slot split kills serialization) ----
#pragma unroll
    for (int q = 0; q < EPT / 4; ++q) {
        unsigned pk = bp[q];
#pragma unroll
        for (int jj = 0; jj < 4; ++jj)
            atomicAdd(&hist0[(pk >> (8 * jj)) & 255u][lane & 7], 1u);
    }
    __syncthreads();                                   // B2

    // merge slots + inclusive suffix scan (shfl) to find crossing bin B*
    unsigned v = 0;
#pragma unroll
    for (int k = 0; k < 8; ++k) v += hist0[t][k];
#pragma unroll
    for (int sft = 1; sft < 64; sft <<= 1) {
        unsigned tmp = __shfl(v, lane + sft);
        v += (lane + sft < 64) ? tmp : 0u;
    }
    if (lane == 0) wtot[w] = v;
    unsigned vnext = __shfl(v, lane + 1);
    __syncthreads();                                   // B3
    unsigned Kr = KSEL;
    {
        unsigned hi = 0;
#pragma unroll
        for (int c = 0; c < 4; ++c) hi += (c > w) ? wtot[c] : 0u;
        unsigned cum     = v + hi;                          // # keys with bin >= t
        unsigned cumNext = ((lane < 63) ? vnext : 0u) + hi; // # keys with bin >  t
        if (cum >= Kr && cumNext < Kr) { sh_digit = (unsigned)t; sh_above = cumNext; }
    }
    __syncthreads();                                   // B4
    const unsigned Bstar = sh_digit;
    Kr -= sh_above;       // rank of threshold within bin B*

    // candidate bitmask: my elements with bin == B*
    unsigned cm = 0;
#pragma unroll
    for (int q = 0; q < EPT / 4; ++q) {
        unsigned pk = bp[q];
#pragma unroll
        for (int jj = 0; jj < 4; ++jj)
            cm |= (((pk >> (8 * jj)) & 255u) == Bstar) ? (1u << (4 * q + jj)) : 0u;
    }

    // ---- exact 4x8-bit MSB radix select restricted to candidates (tiny, conflict-free) ----
    unsigned prefix = 0;
#pragma unroll
    for (int p = 0; p < 4; ++p) {
        const int shift = 24 - 8 * p;
        // wave-private zero (wave-ordered wrt this wave's atomics; cross-wave safe after prior barrier)
        histr[w][lane] = 0; histr[w][lane + 64] = 0; histr[w][lane + 128] = 0; histr[w][lane + 192] = 0;
#pragma unroll
        for (int j = 0; j < EPT; ++j) {
            if ((cm >> j) & 1u) {
                unsigned k = key[j];
                if (p == 0 || (k >> (shift + 8)) == prefix)
                    atomicAdd(&histr[w][(k >> shift) & 255u], 1u);
            }
        }
        __syncthreads();                               // Ba
        unsigned vv = histr[0][t] + histr[1][t] + histr[2][t] + histr[3][t];
#pragma unroll
        for (int sft = 1; sft < 64; sft <<= 1) {
            unsigned tmp = __shfl(vv, lane + sft);
            vv += (lane + sft < 64) ? tmp : 0u;
        }
        if (lane == 0) wtot[w] = vv;
        unsigned vvn = __shfl(vv, lane + 1);
        __syncthreads();                               // Bb
        unsigned hi2 = 0;
#pragma unroll
        for (int c = 0; c < 4; ++c) hi2 += (c > w) ? wtot[c] : 0u;
        unsigned cum2  = vv + hi2;
        unsigned cumN2 = ((lane < 63) ? vvn : 0u) + hi2;
        if (cum2 >= Kr && cumN2 < Kr) { sh_digit = (unsigned)t; sh_above = cumN2; }
        __syncthreads();                               // Bc
        prefix = (prefix << 8) | sh_digit;
        Kr -= sh_above;    // remaining slots among keys equal at this digit
    }
    const unsigned thr = prefix;   // exact K-th largest key; Kr = # equal keys to take

    // ---- lowest-index-first tie selection: exclusive prefix of equal counts ----
    unsigned eq = 0;
#pragma unroll
    for (int j = 0; j < EPT; ++j) eq += (key[j] == thr) ? 1u : 0u;
    unsigned pv = eq;
#pragma unroll
    for (int sft = 1; sft < 64; sft <<= 1) {           // inclusive prefix scan within wave
        unsigned tmp = __shfl(pv, lane - sft);
        pv += (lane >= sft) ? tmp : 0u;
    }
    if (lane == 63) wtot[w] = pv;                      // wave total
    __syncthreads();                                   // Bd
    unsigned offset = 0;
#pragma unroll
    for (int c = 0; c < 4; ++c) offset += (c < w) ? wtot[c] : 0u;
    unsigned pos = offset + pv - eq;

    // ---- write out = x * mask (reload x; L2-warm) ----
    float4* op = reinterpret_cast<float4*>(out + base);
#pragma unroll
    for (int q = 0; q < EPT / 4; ++q) {
        float4 xx = xp[q];
        float xa[4] = {xx.x, xx.y, xx.z, xx.w};
        float vals[4];
#pragma unroll
        for (int jj = 0; jj < 4; ++jj) {
            int j = 4 * q + jj;
            bool sel;
            if (key[j] > thr)       sel = true;
            else if (key[j] == thr) { sel = (pos < Kr); ++pos; }
            else                    sel = false;
            vals[jj] = sel ? xa[jj] : 0.0f;
        }
        float4 o4; o4.x = vals[0]; o4.y = vals[1]; o4.z = vals[2]; o4.w = vals[3];
        op[q] = o4;
    }
}

__global__ void skw_zero(float* p) { *p = 0.0f; }

// Deterministic fixed-order mean of rowH -> out scalar.
__global__ void skw_reduce(const float* __restrict__ rowH, float* __restrict__ outp, int B)
{
    __shared__ float red[256];
    int t = threadIdx.x;
    float s = 0.f;
    for (int i = t; i < B; i += 256) s += rowH[i];
    red[t] = s; __syncthreads();
    for (int st = 128; st > 0; st >>= 1) { if (t < st) red[t] += red[t + st]; __syncthreads(); }
    if (t == 0) *outp = red[0] / (float)B;
}

extern "C" void kernel_launch(void* const* d_in, const int* in_sizes, int n_in,
                              void* d_out, int out_size, void* d_ws, size_t ws_size,
                              hipStream_t stream)
{
    const float* x = (const float*)d_in[0];
    const float* g = (const float*)d_in[1];
    float* out = (float*)d_out;
    const int BN = in_sizes[0];
    const int B  = BN / NN;
    float* entp = out + (size_t)BN;

    if (ws_size >= (size_t)B * sizeof(float)) {
        float* rowH = (float*)d_ws;
        skw_main<true><<<B, TPB, 0, stream>>>(x, g, out, rowH, nullptr, 0.f);
        skw_reduce<<<1, 256, 0, stream>>>(rowH, entp, B);
    } else {
        skw_zero<<<1, 1, 0, stream>>>(entp);
        skw_main<false><<<B, TPB, 0, stream>>>(x, g, out, nullptr, entp, 1.0f / (float)B);
    }
}

// Round 4
// 170.720 us; speedup vs baseline: 1.5218x; 1.5218x over previous
//
#include <hip/hip_runtime.h>
#include <math.h>

#define TPB 256
#define EPT 16      // elements per thread
#define NN  4096    // row length (fixed by problem)
#define KSEL 410    // K = round(4096 * 0.1)

// Monotonic float->uint key: larger float => larger unsigned key.
__device__ __forceinline__ unsigned sortkey(float f) {
    unsigned u = __float_as_uint(f);
    unsigned m = (unsigned)(((int)u) >> 31);     // 0x00000000 or 0xFFFFFFFF
    return u ^ (m | 0x80000000u);
}

template <bool USE_WS>
__global__ __launch_bounds__(TPB)
void skw_main(const float* __restrict__ x, const float* __restrict__ g,
              float* __restrict__ out, float* __restrict__ rowH,
              float* __restrict__ entAcc, float invB)
{
    const int row  = blockIdx.x;
    const int t    = threadIdx.x;
    const int w    = t >> 6;          // wave id 0..3
    const int lane = t & 63;
    const size_t rbase = (size_t)row * NN;

    // Thread t, chunk q owns flat elements q*1024 + t*4 + (0..3):
    // every wave instruction touches a contiguous 1 KB => full-line, no RMW.
    float    xv[EPT];
    unsigned key[EPT];
    unsigned bp[EPT / 4];             // 16 value-domain bins, byte-packed

    __shared__ unsigned hist0[256][9];   // bin pass: 8 slots + 1 pad (stride 9, conflict-free)
    __shared__ unsigned histr[4][256];   // candidate radix: per-wave
    __shared__ unsigned wtot[4];
    __shared__ unsigned wtA[4], wtB[4];
    __shared__ float    fred[8];
    __shared__ unsigned sh_digit, sh_above;

    const float4* xp = reinterpret_cast<const float4*>(x + rbase);
    const float4* gp = reinterpret_cast<const float4*>(g + rbase);
    float4*       op = reinterpret_cast<float4*>(out + rbase);

    // ---- load; entropy partials; exact s = x/10 + g (Markstein div-by-10); value bins ----
    float sZ = 0.f, sZL = 0.f;
#pragma unroll
    for (int q = 0; q < EPT / 4; ++q) {
        float4 xx = xp[(q << 8) + t];
        float4 gg = gp[(q << 8) + t];
        float xa[4] = {xx.x, xx.y, xx.z, xx.w};
        float ga[4] = {gg.x, gg.y, gg.z, gg.w};
        unsigned pk = 0;
#pragma unroll
        for (int jj = 0; jj < 4; ++jj) {
            float xs = xa[jj];
            xv[4 * q + jj] = xs;
            float l = xs * 0.1f;                  // y0 = RN(x * RN(0.1))
            float e = __expf(l);
            sZ  += e;
            sZL += e * l;
            // correctly-rounded x/10: q = y0 + (x - 10*y0)*0.1  (x/10 never at f32 midpoint)
            float q10 = __builtin_fmaf(__builtin_fmaf(-10.0f, l, xs), 0.1f, l);
            float s = q10 + ga[jj];
            key[4 * q + jj] = sortkey(s);
            int b = (int)__builtin_fmaf(s, 16.0f, 64.0f);   // (s+4)*16, monotone in s
            b = min(max(b, 0), 255);
            pk |= (unsigned)b << (8 * jj);
        }
        bp[q] = pk;
    }

    // ---- entropy reduce (m = 0 is safe: |x*0.1| < ~0.6) ----
#pragma unroll
    for (int sft = 32; sft >= 1; sft >>= 1) { sZ += __shfl_xor(sZ, sft); sZL += __shfl_xor(sZL, sft); }
    if (lane == 0) { fred[w] = sZ; fred[4 + w] = sZL; }

    // zero bin histogram (2304 words incl. padding)
    unsigned* h0 = &hist0[0][0];
#pragma unroll
    for (int i = 0; i < 9; ++i) h0[t + 256 * i] = 0;
    __syncthreads();                                   // B1

    if (t == 0) {
        float Z = fred[0] + fred[1] + fred[2] + fred[3];
        float L = fred[4] + fred[5] + fred[6] + fred[7];
        float H = __logf(Z) - L / Z;                   // H = lnZ - E[l]
        if (USE_WS) rowH[row] = H;
        else atomicAdd(entAcc, H * invB);
    }

    // ---- value-bin histogram (near-uniform bins; 8-way slot split kills serialization) ----
#pragma unroll
    for (int q = 0; q < EPT / 4; ++q) {
        unsigned pk = bp[q];
#pragma unroll
        for (int jj = 0; jj < 4; ++jj)
            atomicAdd(&hist0[(pk >> (8 * jj)) & 255u][lane & 7], 1u);
    }
    __syncthreads();                                   // B2

    // merge slots + inclusive suffix scan (shfl) to find crossing bin B*
    unsigned v = 0;
#pragma unroll
    for (int k = 0; k < 8; ++k) v += hist0[t][k];
#pragma unroll
    for (int sft = 1; sft < 64; sft <<= 1) {
        unsigned tmp = __shfl(v, lane + sft);
        v += (lane + sft < 64) ? tmp : 0u;
    }
    if (lane == 0) wtot[w] = v;
    unsigned vnext = __shfl(v, lane + 1);
    __syncthreads();                                   // B3
    unsigned Kr = KSEL;
    {
        unsigned hi = 0;
#pragma unroll
        for (int c = 0; c < 4; ++c) hi += (c > w) ? wtot[c] : 0u;
        unsigned cum     = v + hi;                          // # keys with bin >= t
        unsigned cumNext = ((lane < 63) ? vnext : 0u) + hi; // # keys with bin >  t
        if (cum >= Kr && cumNext < Kr) { sh_digit = (unsigned)t; sh_above = cumNext; }
    }
    __syncthreads();                                   // B4
    const unsigned Bstar = sh_digit;
    Kr -= sh_above;       // rank of threshold within bin B*

    // candidate bitmask: my elements with bin == B*
    unsigned cm = 0;
#pragma unroll
    for (int q = 0; q < EPT / 4; ++q) {
        unsigned pk = bp[q];
#pragma unroll
        for (int jj = 0; jj < 4; ++jj)
            cm |= (((pk >> (8 * jj)) & 255u) == Bstar) ? (1u << (4 * q + jj)) : 0u;
    }

    // ---- exact 4x8-bit MSB radix select restricted to candidates (tiny, conflict-free) ----
    unsigned prefix = 0;
#pragma unroll
    for (int p = 0; p < 4; ++p) {
        const int shift = 24 - 8 * p;
        // wave-private zero (same-wave ordering wrt its own atomics; cross-wave reads are barriered)
        histr[w][lane] = 0; histr[w][lane + 64] = 0; histr[w][lane + 128] = 0; histr[w][lane + 192] = 0;
#pragma unroll
        for (int j = 0; j < EPT; ++j) {
            if ((cm >> j) & 1u) {
                unsigned k = key[j];
                if (p == 0 || (k >> (shift + 8)) == prefix)
                    atomicAdd(&histr[w][(k >> shift) & 255u], 1u);
            }
        }
        __syncthreads();                               // Ba
        unsigned vv = histr[0][t] + histr[1][t] + histr[2][t] + histr[3][t];
#pragma unroll
        for (int sft = 1; sft < 64; sft <<= 1) {
            unsigned tmp = __shfl(vv, lane + sft);
            vv += (lane + sft < 64) ? tmp : 0u;
        }
        if (lane == 0) wtot[w] = vv;
        unsigned vvn = __shfl(vv, lane + 1);
        __syncthreads();                               // Bb
        unsigned hi2 = 0;
#pragma unroll
        for (int c = 0; c < 4; ++c) hi2 += (c > w) ? wtot[c] : 0u;
        unsigned cum2  = vv + hi2;
        unsigned cumN2 = ((lane < 63) ? vvn : 0u) + hi2;
        if (cum2 >= Kr && cumN2 < Kr) { sh_digit = (unsigned)t; sh_above = cumN2; }
        __syncthreads();                               // Bc
        prefix = (prefix << 8) | sh_digit;
        Kr -= sh_above;    // remaining slots among keys equal at this digit
    }
    const unsigned thr = prefix;   // exact K-th largest key; Kr = # equal keys to take

    // ===== lowest-index-first ties, column order c = q*1024 + t*4 + jj =====
    // Per-q equal counts, packed 16-bit prefix scans (worst-case half-total 1024 < 2^16).
    unsigned eq[4];
#pragma unroll
    for (int q = 0; q < 4; ++q) {
        unsigned e = 0;
#pragma unroll
        for (int jj = 0; jj < 4; ++jj) e += (key[4 * q + jj] == thr) ? 1u : 0u;
        eq[q] = e;
    }
    unsigned wA = eq[0] | (eq[1] << 16);
    unsigned wB = eq[2] | (eq[3] << 16);
    unsigned sA = wA, sB = wB;
#pragma unroll
    for (int sft = 1; sft < 64; sft <<= 1) {           // inclusive prefix scan within wave
        unsigned ta = __shfl(sA, lane - sft);
        unsigned tb = __shfl(sB, lane - sft);
        if (lane >= sft) { sA += ta; sB += tb; }
    }
    if (lane == 63) { wtA[w] = sA; wtB[w] = sB; }
    __syncthreads();                                   // Bd
    unsigned offA = 0, offB = 0, totA = 0, totB = 0;
#pragma unroll
    for (int c = 0; c < 4; ++c) {
        totA += wtA[c]; totB += wtB[c];
        if (c < w) { offA += wtA[c]; offB += wtB[c]; }
    }
    unsigned exA = offA + sA - wA;                     // exclusive prefix (earlier threads), packed
    unsigned exB = offB + sB - wB;
    unsigned tot0 = totA & 0xFFFFu, tot1 = totA >> 16, tot2 = totB & 0xFFFFu;
    unsigned baseq[4] = {0u, tot0, tot0 + tot1, tot0 + tot1 + tot2};
    unsigned exq[4]   = {exA & 0xFFFFu, exA >> 16, exB & 0xFFFFu, exB >> 16};

    // ---- write out = x * mask (coalesced full-line stores) ----
#pragma unroll
    for (int q = 0; q < EPT / 4; ++q) {
        unsigned pos = baseq[q] + exq[q];              // equals before my first element of this q
        float vals[4];
#pragma unroll
        for (int jj = 0; jj < 4; ++jj) {
            int j = 4 * q + jj;
            bool sel;
            if (key[j] > thr)       sel = true;
            else if (key[j] == thr) { sel = (pos < Kr); ++pos; }
            else                    sel = false;
            vals[jj] = sel ? xv[j] : 0.0f;
        }
        float4 o4; o4.x = vals[0]; o4.y = vals[1]; o4.z = vals[2]; o4.w = vals[3];
        op[(q << 8) + t] = o4;
    }
}

__global__ void skw_zero(float* p) { *p = 0.0f; }

// Deterministic fixed-order mean of rowH -> out scalar.
__global__ void skw_reduce(const float* __restrict__ rowH, float* __restrict__ outp, int B)
{
    __shared__ float red[256];
    int t = threadIdx.x;
    float s = 0.f;
    for (int i = t; i < B; i += 256) s += rowH[i];
    red[t] = s; __syncthreads();
    for (int st = 128; st > 0; st >>= 1) { if (t < st) red[t] += red[t + st]; __syncthreads(); }
    if (t == 0) *outp = red[0] / (float)B;
}

extern "C" void kernel_launch(void* const* d_in, const int* in_sizes, int n_in,
                              void* d_out, int out_size, void* d_ws, size_t ws_size,
                              hipStream_t stream)
{
    const float* x = (const float*)d_in[0];
    const float* g = (const float*)d_in[1];
    float* out = (float*)d_out;
    const int BN = in_sizes[0];
    const int B  = BN / NN;
    float* entp = out + (size_t)BN;

    if (ws_size >= (size_t)B * sizeof(float)) {
        float* rowH = (float*)d_ws;
        skw_main<true><<<B, TPB, 0, stream>>>(x, g, out, rowH, nullptr, 0.f);
        skw_reduce<<<1, 256, 0, stream>>>(rowH, entp, B);
    } else {
        skw_zero<<<1, 1, 0, stream>>>(entp);
        skw_main<false><<<B, TPB, 0, stream>>>(x, g, out, nullptr, entp, 1.0f / (float)B);
    }
}

// Round 6
// 166.868 us; speedup vs baseline: 1.5569x; 1.0231x over previous
//
#include <hip/hip_runtime.h>
#include <math.h>

#define TPB 256
#define EPT 16      // elements per thread
#define NN  4096    // row length (fixed by problem)
#define KSEL 410    // K = round(4096 * 0.1)
#define CAP 1024    // candidate list capacity (>=97 sigma above expected max ~94)

typedef float floatx4 __attribute__((ext_vector_type(4)));   // native vector for nontemporal store

// Monotonic float->uint key: larger float => larger unsigned key.
__device__ __forceinline__ unsigned sortkey(float f) {
    unsigned u = __float_as_uint(f);
    unsigned m = (unsigned)(((int)u) >> 31);     // 0x00000000 or 0xFFFFFFFF
    return u ^ (m | 0x80000000u);
}

template <bool USE_WS>
__global__ __launch_bounds__(TPB)
void skw_main(const float* __restrict__ x, const float* __restrict__ g,
              float* __restrict__ out, float* __restrict__ rowH,
              float* __restrict__ entAcc, float invB)
{
    const int row  = blockIdx.x;
    const int t    = threadIdx.x;
    const int w    = t >> 6;          // wave id 0..3
    const int lane = t & 63;
    const size_t rbase = (size_t)row * NN;

    // Thread t, chunk q owns flat elements q*1024 + t*4 + (0..3):
    // every wave instruction touches a contiguous 1 KB => full-line, no RMW.
    float    xv[EPT];
    unsigned key[EPT];
    unsigned bp[EPT / 4];             // 16 value-domain bins, byte-packed

    __shared__ unsigned hist0[256][9];   // bin histogram: 8 slots + 1 pad (stride 9)
    __shared__ unsigned wtot[4];
    __shared__ unsigned wtA[4], wtB[4];
    __shared__ float    fred[8];
    __shared__ unsigned sh_digit, sh_above, sh_cnt, sh_thr, sh_take;

    unsigned* list = &hist0[0][0];       // aliases hist0; only written after B4 (hist0 dead)

    const float4* xp = reinterpret_cast<const float4*>(x + rbase);
    const float4* gp = reinterpret_cast<const float4*>(g + rbase);
    floatx4*      op = reinterpret_cast<floatx4*>(out + rbase);

    // ---- load; entropy partials; exact s = x/10 + g (Markstein div-by-10); value bins ----
    float sZ = 0.f, sZL = 0.f;
#pragma unroll
    for (int q = 0; q < EPT / 4; ++q) {
        float4 xx = xp[(q << 8) + t];
        float4 gg = gp[(q << 8) + t];
        float xa[4] = {xx.x, xx.y, xx.z, xx.w};
        float ga[4] = {gg.x, gg.y, gg.z, gg.w};
        unsigned pk = 0;
#pragma unroll
        for (int jj = 0; jj < 4; ++jj) {
            float xs = xa[jj];
            xv[4 * q + jj] = xs;
            float l = xs * 0.1f;                  // y0 = RN(x * RN(0.1))
            float e = __expf(l);
            sZ  += e;
            sZL = __builtin_fmaf(e, l, sZL);
            // correctly-rounded x/10: q = y0 + (x - 10*y0)*0.1  (x/10 never at f32 midpoint)
            float q10 = __builtin_fmaf(__builtin_fmaf(-10.0f, l, xs), 0.1f, l);
            float s = q10 + ga[jj];
            key[4 * q + jj] = sortkey(s);
            int b = (int)__builtin_fmaf(s, 16.0f, 64.0f);   // (s+4)*16, monotone in s
            b = min(max(b, 0), 255);
            pk |= (unsigned)b << (8 * jj);
        }
        bp[q] = pk;
    }

    // ---- entropy reduce (m = 0 is safe: |x*0.1| < ~0.6) ----
#pragma unroll
    for (int sft = 32; sft >= 1; sft >>= 1) { sZ += __shfl_xor(sZ, sft); sZL += __shfl_xor(sZL, sft); }
    if (lane == 0) { fred[w] = sZ; fred[4 + w] = sZL; }

    // zero bin histogram (+ counter)
    unsigned* h0 = &hist0[0][0];
#pragma unroll
    for (int i = 0; i < 9; ++i) h0[t + 256 * i] = 0;
    if (t == 0) sh_cnt = 0;
    __syncthreads();                                   // B1

    if (t == 0) {
        float Z = fred[0] + fred[1] + fred[2] + fred[3];
        float L = fred[4] + fred[5] + fred[6] + fred[7];
        float H = __logf(Z) - L / Z;                   // H = lnZ - E[l]
        if (USE_WS) rowH[row] = H;
        else atomicAdd(entAcc, H * invB);
    }

    // ---- value-bin histogram (near-uniform bins; 8-way slot split kills serialization) ----
#pragma unroll
    for (int q = 0; q < EPT / 4; ++q) {
        unsigned pk = bp[q];
#pragma unroll
        for (int jj = 0; jj < 4; ++jj)
            atomicAdd(&hist0[(pk >> (8 * jj)) & 255u][lane & 7], 1u);
    }
    __syncthreads();                                   // B2

    // merge slots + inclusive suffix scan (shfl) to find crossing bin B*
    unsigned v = 0;
#pragma unroll
    for (int k = 0; k < 8; ++k) v += hist0[t][k];
#pragma unroll
    for (int sft = 1; sft < 64; sft <<= 1) {
        unsigned tmp = __shfl(v, lane + sft);
        v += (lane + sft < 64) ? tmp : 0u;
    }
    if (lane == 0) wtot[w] = v;
    unsigned vnext = __shfl(v, lane + 1);
    __syncthreads();                                   // B3
    unsigned Kr = KSEL;
    {
        unsigned hi = 0;
#pragma unroll
        for (int c = 0; c < 4; ++c) hi += (c > w) ? wtot[c] : 0u;
        unsigned cum     = v + hi;                          // # keys with bin >= t
        unsigned cumNext = ((lane < 63) ? vnext : 0u) + hi; // # keys with bin >  t
        if (cum >= Kr && cumNext < Kr) { sh_digit = (unsigned)t; sh_above = cumNext; }
    }
    __syncthreads();                                   // B4
    const unsigned Bstar = sh_digit;
    Kr -= sh_above;       // 1-based rank of threshold within bin B* (from largest)

    // ---- append candidates (bin == B*) to LDS list; exact rank among ~25-95 keys ----
    unsigned cm = 0;
#pragma unroll
    for (int q = 0; q < EPT / 4; ++q) {
        unsigned pk = bp[q];
#pragma unroll
        for (int jj = 0; jj < 4; ++jj)
            cm |= (((pk >> (8 * jj)) & 255u) == Bstar) ? (1u << (4 * q + jj)) : 0u;
    }
#pragma unroll
    for (int j = 0; j < EPT; ++j) {
        if ((cm >> j) & 1u) {
            unsigned p = atomicAdd(&sh_cnt, 1u);
            if (p < CAP) list[p] = key[j];
        }
    }
    __syncthreads();                                   // B5

    const unsigned M = sh_cnt;                         // = count of keys in bin B*
    for (unsigned i = t; i < M; i += TPB) {
        unsigned ki = list[i];
        unsigned gt = 0, eqc = 0;
        for (unsigned j2 = 0; j2 < M; ++j2) {
            unsigned kj = list[j2];                    // broadcast read
            gt  += (kj > ki) ? 1u : 0u;
            eqc += (kj == ki) ? 1u : 0u;
        }
        if (gt < Kr && Kr <= gt + eqc) { sh_thr = ki; sh_take = Kr - gt; }  // unique value
    }
    __syncthreads();                                   // B6
    const unsigned thr    = sh_thr;    // exact K-th largest key overall
    const unsigned KrTake = sh_take;   // # equal keys to accept (lowest column index first)

    // ===== lowest-index-first ties, column order c = q*1024 + t*4 + jj =====
    unsigned eq[4];
#pragma unroll
    for (int q = 0; q < 4; ++q) {
        unsigned e = 0;
#pragma unroll
        for (int jj = 0; jj < 4; ++jj) e += (key[4 * q + jj] == thr) ? 1u : 0u;
        eq[q] = e;
    }
    unsigned wA = eq[0] | (eq[1] << 16);
    unsigned wB = eq[2] | (eq[3] << 16);
    unsigned sA = wA, sB = wB;
#pragma unroll
    for (int sft = 1; sft < 64; sft <<= 1) {           // inclusive prefix scan within wave
        unsigned ta = __shfl(sA, lane - sft);
        unsigned tb = __shfl(sB, lane - sft);
        if (lane >= sft) { sA += ta; sB += tb; }
    }
    if (lane == 63) { wtA[w] = sA; wtB[w] = sB; }
    __syncthreads();                                   // Bd
    unsigned offA = 0, offB = 0, totA = 0, totB = 0;
#pragma unroll
    for (int c = 0; c < 4; ++c) {
        totA += wtA[c]; totB += wtB[c];
        if (c < w) { offA += wtA[c]; offB += wtB[c]; }
    }
    unsigned exA = offA + sA - wA;                     // exclusive prefix (earlier threads), packed
    unsigned exB = offB + sB - wB;
    unsigned tot0 = totA & 0xFFFFu, tot1 = totA >> 16, tot2 = totB & 0xFFFFu;
    unsigned baseq[4] = {0u, tot0, tot0 + tot1, tot0 + tot1 + tot2};
    unsigned exq[4]   = {exA & 0xFFFFu, exA >> 16, exB & 0xFFFFu, exB >> 16};

    // ---- write out = x * mask (coalesced full-line nontemporal stores) ----
#pragma unroll
    for (int q = 0; q < EPT / 4; ++q) {
        unsigned pos = baseq[q] + exq[q];              // equals before my first element of this q
        float vals[4];
#pragma unroll
        for (int jj = 0; jj < 4; ++jj) {
            int j = 4 * q + jj;
            bool sel;
            if (key[j] > thr)       sel = true;
            else if (key[j] == thr) { sel = (pos < KrTake); ++pos; }
            else                    sel = false;
            vals[jj] = sel ? xv[j] : 0.0f;
        }
        floatx4 o4;
        o4.x = vals[0]; o4.y = vals[1]; o4.z = vals[2]; o4.w = vals[3];
        __builtin_nontemporal_store(o4, &op[(q << 8) + t]);
    }
}

__global__ void skw_zero(float* p) { *p = 0.0f; }

// Deterministic fixed-order mean of rowH -> out scalar.
__global__ void skw_reduce(const float* __restrict__ rowH, float* __restrict__ outp, int B)
{
    __shared__ float red[256];
    int t = threadIdx.x;
    float s = 0.f;
    for (int i = t; i < B; i += 256) s += rowH[i];
    red[t] = s; __syncthreads();
    for (int st = 128; st > 0; st >>= 1) { if (t < st) red[t] += red[t + st]; __syncthreads(); }
    if (t == 0) *outp = red[0] / (float)B;
}

extern "C" void kernel_launch(void* const* d_in, const int* in_sizes, int n_in,
                              void* d_out, int out_size, void* d_ws, size_t ws_size,
                              hipStream_t stream)
{
    const float* x = (const float*)d_in[0];
    const float* g = (const float*)d_in[1];
    float* out = (float*)d_out;
    const int BN = in_sizes[0];
    const int B  = BN / NN;
    float* entp = out + (size_t)BN;

    if (ws_size >= (size_t)B * sizeof(float)) {
        float* rowH = (float*)d_ws;
        skw_main<true><<<B, TPB, 0, stream>>>(x, g, out, rowH, nullptr, 0.f);
        skw_reduce<<<1, 256, 0, stream>>>(rowH, entp, B);
    } else {
        skw_zero<<<1, 1, 0, stream>>>(entp);
        skw_main<false><<<B, TPB, 0, stream>>>(x, g, out, nullptr, entp, 1.0f / (float)B);
    }
}

// Round 7
// 165.312 us; speedup vs baseline: 1.5716x; 1.0094x over previous
//
#include <hip/hip_runtime.h>
#include <math.h>

#define TPB 256
#define EPT 16      // elements per thread
#define NN  4096    // row length (fixed by problem)
#define KSEL 410    // K = round(4096 * 0.1)
#define CAP 1024    // candidate list capacity (>=97 sigma above expected max ~94)

typedef float floatx4 __attribute__((ext_vector_type(4)));   // native vector for nontemporal store

// Monotonic float->uint key: larger float => larger unsigned key.
__device__ __forceinline__ unsigned sortkey(float f) {
    unsigned u = __float_as_uint(f);
    unsigned m = (unsigned)(((int)u) >> 31);     // 0x00000000 or 0xFFFFFFFF
    return u ^ (m | 0x80000000u);
}

template <bool USE_WS>
__global__ __launch_bounds__(TPB)
void skw_main(const float* __restrict__ x, const float* __restrict__ g,
              float* __restrict__ out, float* __restrict__ rowH,
              float* __restrict__ entAcc, float invB)
{
    const int row  = blockIdx.x;
    const int t    = threadIdx.x;
    const int w    = t >> 6;          // wave id 0..3
    const int lane = t & 63;
    const size_t rbase = (size_t)row * NN;

    float    xv[EPT];
    unsigned key[EPT];
    unsigned bp[EPT / 4];             // 16 value-domain bins, byte-packed

    __shared__ unsigned hist0[256][9];   // bin histogram: 8 slots + 1 pad (stride 9)
    __shared__ unsigned wtot[4];
    __shared__ unsigned wtA[4], wtB[4];
    __shared__ float    fred[8];
    __shared__ unsigned sh_digit, sh_above, sh_cnt, sh_thr, sh_take;

    unsigned* list = &hist0[0][0];       // aliases hist0; only written after B4 (hist0 dead)

    const float4* xp = reinterpret_cast<const float4*>(x + rbase);
    const float4* gp = reinterpret_cast<const float4*>(g + rbase);
    floatx4*      op = reinterpret_cast<floatx4*>(out + rbase);

    // ---- PHASE 1a: issue ALL global loads up-front (8 x 1KB/wave in flight) ----
    // Interleaved x/g so the q=0 consumer only needs vmcnt(6); the other 6 loads
    // keep streaming under the key/exp computation below.
    float4 xx[EPT / 4], gg[EPT / 4];
#pragma unroll
    for (int q = 0; q < EPT / 4; ++q) {
        xx[q] = xp[(q << 8) + t];
        gg[q] = gp[(q << 8) + t];
    }

    // ---- PHASE 1b: entropy partials; exact s = x/10 + g (Markstein); value bins ----
    float sZ = 0.f, sZL = 0.f;
#pragma unroll
    for (int q = 0; q < EPT / 4; ++q) {
        float xa[4] = {xx[q].x, xx[q].y, xx[q].z, xx[q].w};
        float ga[4] = {gg[q].x, gg[q].y, gg[q].z, gg[q].w};
        unsigned pk = 0;
#pragma unroll
        for (int jj = 0; jj < 4; ++jj) {
            float xs = xa[jj];
            xv[4 * q + jj] = xs;
            float l = xs * 0.1f;                  // y0 = RN(x * RN(0.1))
            float e = __expf(l);
            sZ  += e;
            sZL = __builtin_fmaf(e, l, sZL);
            // correctly-rounded x/10: q = y0 + (x - 10*y0)*0.1  (x/10 never at f32 midpoint)
            float q10 = __builtin_fmaf(__builtin_fmaf(-10.0f, l, xs), 0.1f, l);
            float s = q10 + ga[jj];
            key[4 * q + jj] = sortkey(s);
            int b = (int)__builtin_fmaf(s, 16.0f, 64.0f);   // (s+4)*16, monotone in s
            b = min(max(b, 0), 255);
            pk |= (unsigned)b << (8 * jj);
        }
        bp[q] = pk;
    }

    // ---- entropy reduce (m = 0 is safe: |x*0.1| < ~0.6) ----
#pragma unroll
    for (int sft = 32; sft >= 1; sft >>= 1) { sZ += __shfl_xor(sZ, sft); sZL += __shfl_xor(sZL, sft); }
    if (lane == 0) { fred[w] = sZ; fred[4 + w] = sZL; }

    // zero bin histogram (+ counter)
    unsigned* h0 = &hist0[0][0];
#pragma unroll
    for (int i = 0; i < 9; ++i) h0[t + 256 * i] = 0;
    if (t == 0) sh_cnt = 0;
    __syncthreads();                                   // B1

    if (t == 0) {
        float Z = fred[0] + fred[1] + fred[2] + fred[3];
        float L = fred[4] + fred[5] + fred[6] + fred[7];
        float H = __logf(Z) - L / Z;                   // H = lnZ - E[l]
        if (USE_WS) rowH[row] = H;
        else atomicAdd(entAcc, H * invB);
    }

    // ---- value-bin histogram (near-uniform bins; 8-way slot split kills serialization) ----
#pragma unroll
    for (int q = 0; q < EPT / 4; ++q) {
        unsigned pk = bp[q];
#pragma unroll
        for (int jj = 0; jj < 4; ++jj)
            atomicAdd(&hist0[(pk >> (8 * jj)) & 255u][lane & 7], 1u);
    }
    __syncthreads();                                   // B2

    // merge slots + inclusive suffix scan (shfl) to find crossing bin B*
    unsigned v = 0;
#pragma unroll
    for (int k = 0; k < 8; ++k) v += hist0[t][k];
#pragma unroll
    for (int sft = 1; sft < 64; sft <<= 1) {
        unsigned tmp = __shfl(v, lane + sft);
        v += (lane + sft < 64) ? tmp : 0u;
    }
    if (lane == 0) wtot[w] = v;
    unsigned vnext = __shfl(v, lane + 1);
    __syncthreads();                                   // B3
    unsigned Kr = KSEL;
    {
        unsigned hi = 0;
#pragma unroll
        for (int c = 0; c < 4; ++c) hi += (c > w) ? wtot[c] : 0u;
        unsigned cum     = v + hi;                          // # keys with bin >= t
        unsigned cumNext = ((lane < 63) ? vnext : 0u) + hi; // # keys with bin >  t
        if (cum >= Kr && cumNext < Kr) { sh_digit = (unsigned)t; sh_above = cumNext; }
    }
    __syncthreads();                                   // B4
    const unsigned Bstar = sh_digit;
    Kr -= sh_above;       // 1-based rank of threshold within bin B* (from largest)

    // ---- append candidates (bin == B*) to LDS list; exact rank among ~25-95 keys ----
    unsigned cm = 0;
#pragma unroll
    for (int q = 0; q < EPT / 4; ++q) {
        unsigned pk = bp[q];
#pragma unroll
        for (int jj = 0; jj < 4; ++jj)
            cm |= (((pk >> (8 * jj)) & 255u) == Bstar) ? (1u << (4 * q + jj)) : 0u;
    }
#pragma unroll
    for (int j = 0; j < EPT; ++j) {
        if ((cm >> j) & 1u) {
            unsigned p = atomicAdd(&sh_cnt, 1u);
            if (p < CAP) list[p] = key[j];
        }
    }
    __syncthreads();                                   // B5

    const unsigned M = sh_cnt;                         // = count of keys in bin B*
    for (unsigned i = t; i < M; i += TPB) {
        unsigned ki = list[i];
        unsigned gt = 0, eqc = 0;
        for (unsigned j2 = 0; j2 < M; ++j2) {
            unsigned kj = list[j2];                    // broadcast read
            gt  += (kj > ki) ? 1u : 0u;
            eqc += (kj == ki) ? 1u : 0u;
        }
        if (gt < Kr && Kr <= gt + eqc) { sh_thr = ki; sh_take = Kr - gt; }  // unique value
    }
    __syncthreads();                                   // B6
    const unsigned thr    = sh_thr;    // exact K-th largest key overall
    const unsigned KrTake = sh_take;   // # equal keys to accept (lowest column index first)

    // ===== lowest-index-first ties, column order c = q*1024 + t*4 + jj =====
    unsigned eq[4];
#pragma unroll
    for (int q = 0; q < 4; ++q) {
        unsigned e = 0;
#pragma unroll
        for (int jj = 0; jj < 4; ++jj) e += (key[4 * q + jj] == thr) ? 1u : 0u;
        eq[q] = e;
    }
    unsigned wA = eq[0] | (eq[1] << 16);
    unsigned wB = eq[2] | (eq[3] << 16);
    unsigned sA = wA, sB = wB;
#pragma unroll
    for (int sft = 1; sft < 64; sft <<= 1) {           // inclusive prefix scan within wave
        unsigned ta = __shfl(sA, lane - sft);
        unsigned tb = __shfl(sB, lane - sft);
        if (lane >= sft) { sA += ta; sB += tb; }
    }
    if (lane == 63) { wtA[w] = sA; wtB[w] = sB; }
    __syncthreads();                                   // Bd
    unsigned offA = 0, offB = 0, totA = 0, totB = 0;
#pragma unroll
    for (int c = 0; c < 4; ++c) {
        totA += wtA[c]; totB += wtB[c];
        if (c < w) { offA += wtA[c]; offB += wtB[c]; }
    }
    unsigned exA = offA + sA - wA;                     // exclusive prefix (earlier threads), packed
    unsigned exB = offB + sB - wB;
    unsigned tot0 = totA & 0xFFFFu, tot1 = totA >> 16, tot2 = totB & 0xFFFFu;
    unsigned baseq[4] = {0u, tot0, tot0 + tot1, tot0 + tot1 + tot2};
    unsigned exq[4]   = {exA & 0xFFFFu, exA >> 16, exB & 0xFFFFu, exB >> 16};

    // ---- write out = x * mask (coalesced full-line nontemporal stores) ----
#pragma unroll
    for (int q = 0; q < EPT / 4; ++q) {
        unsigned pos = baseq[q] + exq[q];              // equals before my first element of this q
        float vals[4];
#pragma unroll
        for (int jj = 0; jj < 4; ++jj) {
            int j = 4 * q + jj;
            bool sel;
            if (key[j] > thr)       sel = true;
            else if (key[j] == thr) { sel = (pos < KrTake); ++pos; }
            else                    sel = false;
            vals[jj] = sel ? xv[j] : 0.0f;
        }
        floatx4 o4;
        o4.x = vals[0]; o4.y = vals[1]; o4.z = vals[2]; o4.w = vals[3];
        __builtin_nontemporal_store(o4, &op[(q << 8) + t]);
    }
}

__global__ void skw_zero(float* p) { *p = 0.0f; }

// Deterministic fixed-order mean of rowH -> out scalar.
__global__ void skw_reduce(const float* __restrict__ rowH, float* __restrict__ outp, int B)
{
    __shared__ float red[256];
    int t = threadIdx.x;
    float s = 0.f;
    for (int i = t; i < B; i += 256) s += rowH[i];
    red[t] = s; __syncthreads();
    for (int st = 128; st > 0; st >>= 1) { if (t < st) red[t] += red[t + st]; __syncthreads(); }
    if (t == 0) *outp = red[0] / (float)B;
}

extern "C" void kernel_launch(void* const* d_in, const int* in_sizes, int n_in,
                              void* d_out, int out_size, void* d_ws, size_t ws_size,
                              hipStream_t stream)
{
    const float* x = (const float*)d_in[0];
    const float* g = (const float*)d_in[1];
    float* out = (float*)d_out;
    const int BN = in_sizes[0];
    const int B  = BN / NN;
    float* entp = out + (size_t)BN;

    if (ws_size >= (size_t)B * sizeof(float)) {
        float* rowH = (float*)d_ws;
        skw_main<true><<<B, TPB, 0, stream>>>(x, g, out, rowH, nullptr, 0.f);
        skw_reduce<<<1, 256, 0, stream>>>(rowH, entp, B);
    } else {
        skw_zero<<<1, 1, 0, stream>>>(entp);
        skw_main<false><<<B, TPB, 0, stream>>>(x, g, out, nullptr, entp, 1.0f / (float)B);
    }
}